// Round 6
// baseline (782.193 us; speedup 1.0000x reference)
//
#include <hip/hip_runtime.h>
#include <cstdint>
#include <cstddef>

#define IN_F  4096
#define OUT_F 16384
#define NROWS 8192   // 2*4096 tokens
#define NKT   64     // K-tiles of 64 bytes

typedef __attribute__((ext_vector_type(4)))  int int32x4;
typedef __attribute__((ext_vector_type(16))) int int32x16;

// async global->LDS, 16B/lane (dest = wave-uniform base, HW adds lane*16)
__device__ __forceinline__ void gload_lds16(const void* g, void* s) {
    __builtin_amdgcn_global_load_lds((const __attribute__((address_space(1))) void*)g,
                                     (__attribute__((address_space(3))) void*)s,
                                     16, 0, 0);
}

// ---------------------------------------------------------------------------
// Layouts (fragment-major, shared by producers and GEMM):
//   xqS: [mtile 32][kt 64][c 4][row 256][16B]   c = ksub*2+kh, k = kt*64+c*16..+16
//   wtS: [ntile 64][kt 64][c 4][col 256][16B]
// ---------------------------------------------------------------------------

// Kernel 1: weight [K=4096][N=16384] int32 -> wtS (narrow + transpose + tile)
__global__ __launch_bounds__(256) void transpose_kernel(const int* __restrict__ w,
                                                        uint8_t* __restrict__ wtS) {
    __shared__ uint8_t tile[64][68];
    const int t  = threadIdx.x;
    const int nb = blockIdx.x * 64;
    const int kt = blockIdx.y;          // K-tile = 64 k-rows
    const int kb = kt * 64;

#pragma unroll
    for (int p = 0; p < 4; ++p) {
        const int r = p * 16 + (t >> 4);
        const int c4 = t & 15;
        int4 u = *reinterpret_cast<const int4*>(w + (size_t)(kb + r) * OUT_F + nb + c4 * 4);
        uint32_t packed = (uint32_t)(u.x & 255) | ((uint32_t)(u.y & 255) << 8)
                        | ((uint32_t)(u.z & 255) << 16) | ((uint32_t)(u.w & 255) << 24);
        *reinterpret_cast<uint32_t*>(&tile[r][c4 * 4]) = packed;
    }
    __syncthreads();

    const int col = t >> 2;             // 0..63
    const int c   = t & 3;              // ksub*2+kh
    uint4 o;
    uint32_t* op = reinterpret_cast<uint32_t*>(&o);
#pragma unroll
    for (int j = 0; j < 4; ++j) {
        const int kk = c * 16 + j * 4;
        op[j] = (uint32_t)tile[kk][col] | ((uint32_t)tile[kk + 1][col] << 8)
              | ((uint32_t)tile[kk + 2][col] << 16) | ((uint32_t)tile[kk + 3][col] << 24);
    }
    const int ntile = nb >> 8;
    const int colg  = (nb & 255) + col;
    *reinterpret_cast<uint4*>(wtS + (((size_t)ntile * NKT + kt) * 4 + c) * 4096 + colg * 16) = o;
}

// Kernel 2: per-row dynamic quant -> xqS (fragment-major) + xs
__global__ __launch_bounds__(256) void quant_kernel(const float* __restrict__ x,
                                                    uint8_t* __restrict__ xqS,
                                                    float* __restrict__ xs) {
    const int t = threadIdx.x;
    const int w = t >> 6, l = t & 63;
    const int half = l >> 5, lh = l & 31;
    const int m = blockIdx.x * 8 + w * 2 + half;
    const float* xr = x + (size_t)m * IN_F;

    float am = 0.0f;
#pragma unroll 8
    for (int jj = 0; jj < 32; ++jj) {
        float4 v = reinterpret_cast<const float4*>(xr)[jj * 32 + lh];
        am = fmaxf(am, fmaxf(fmaxf(fabsf(v.x), fabsf(v.y)),
                             fmaxf(fabsf(v.z), fabsf(v.w))));
    }
#pragma unroll
    for (int off = 16; off; off >>= 1) am = fmaxf(am, __shfl_xor(am, off));

    const float scale = fmaxf(am / 127.0f, 1e-12f);
    if (lh == 0) xs[m] = scale;

    const int mtile = m >> 8, mrow = m & 255;
    uint8_t* ob = xqS + (size_t)mtile * (NKT * 16384) + (size_t)mrow * 16;
#pragma unroll
    for (int j = 0; j < 8; ++j) {
        const int k0 = lh * 128 + j * 16;
        const float4* vp = reinterpret_cast<const float4*>(xr + k0);
        uint4 pk;
        uint32_t* pp = reinterpret_cast<uint32_t*>(&pk);
#pragma unroll
        for (int q = 0; q < 4; ++q) {
            float4 v = vp[q];
            float r0 = fminf(127.f, fmaxf(-128.f, rintf(v.x / scale)));
            float r1 = fminf(127.f, fmaxf(-128.f, rintf(v.y / scale)));
            float r2 = fminf(127.f, fmaxf(-128.f, rintf(v.z / scale)));
            float r3 = fminf(127.f, fmaxf(-128.f, rintf(v.w / scale)));
            pp[q] = ((uint32_t)((int)r0 & 255)) | ((uint32_t)((int)r1 & 255) << 8)
                  | ((uint32_t)((int)r2 & 255) << 16) | ((uint32_t)((int)r3 & 255) << 24);
        }
        const int ktk = k0 >> 6;
        const int c   = (k0 >> 4) & 3;
        *reinterpret_cast<uint4*>(ob + ((size_t)ktk * 4 + c) * 4096) = pk;
    }
}

// ---------------------------------------------------------------------------
// Kernel 3: int8 GEMM, 256x256 tile, 8 waves (2Mx4N). A: LDS quad-buffer,
// depth-3 global_load_lds staging, reg-double-buffered fragments. B: global
// (L2-resident) -> VGPR, double-buffered via unroll-2. LDS pipe demand drops
// under the MFMA window; B traffic rides the idle vmem pipe.
// ---------------------------------------------------------------------------
#define GEMM_STEP(KT, BC, BNX)                                                        \
    {                                                                                 \
        const int q  = ((KT) & 3) * 16384;                                            \
        const int q1 = (((KT) + 1) & 3) * 16384;                                      \
        const int q3 = (((KT) + 3) & 3) * 16384;                                      \
        if ((KT) < NKT - 1) {  /* B loads for tile KT+1 (compiler-tracked vmcnt) */   \
            const uint8_t* bsrc = bBase + (size_t)((KT) + 1) * 16384 + bOff;          \
            BNX[0] = *reinterpret_cast<const int32x4*>(bsrc);                         \
            BNX[1] = *reinterpret_cast<const int32x4*>(bsrc + 512);                   \
            BNX[2] = *reinterpret_cast<const int32x4*>(bsrc + 8192);                  \
            BNX[3] = *reinterpret_cast<const int32x4*>(bsrc + 8704);                  \
        }                                                                             \
        _Pragma("unroll")  /* A ds_reads (KT, s=1) -> f1, overlap MFMA f0 */          \
        for (int mr = 0; mr < 4; ++mr)                                                \
            af1[mr] = *reinterpret_cast<const int32x4*>(ldsA + q + 8192 + aRd0 + mr * 512); \
        if ((KT) < NKT - 3) {  /* stage A tile KT+3 (WAR: freed last barrier) */      \
            _Pragma("unroll")                                                         \
            for (int L = 0; L < 2; ++L)                                               \
                gload_lds16(aBase + (size_t)((KT) + 3) * 16384 + L * 8192 + t16,      \
                            ldsA + q3 + L * 8192 + wofs);                             \
        }                                                                             \
        __builtin_amdgcn_s_setprio(1);                                                \
        _Pragma("unroll")                                                             \
        for (int mr = 0; mr < 4; ++mr) {                                              \
            acc[mr][0] = __builtin_amdgcn_mfma_i32_32x32x32_i8(af0[mr], BC[0], acc[mr][0], 0, 0, 0); \
            acc[mr][1] = __builtin_amdgcn_mfma_i32_32x32x32_i8(af0[mr], BC[1], acc[mr][1], 0, 0, 0); \
        }                                                                             \
        __builtin_amdgcn_s_setprio(0);                                                \
        if ((KT) < NKT - 1) {                                                         \
            asm volatile("s_waitcnt lgkmcnt(0)" ::: "memory"); /* WAR drain */        \
            asm volatile("s_waitcnt vmcnt(8)" ::: "memory");   /* Ast(KT+1) landed */ \
            __builtin_amdgcn_s_barrier();                                             \
            __builtin_amdgcn_sched_barrier(0);                                        \
            _Pragma("unroll")  /* A ds_reads (KT+1, s=0) -> f0, overlap MFMA f1 */    \
            for (int mr = 0; mr < 4; ++mr)                                            \
                af0[mr] = *reinterpret_cast<const int32x4*>(ldsA + q1 + aRd0 + mr * 512); \
        }                                                                             \
        __builtin_amdgcn_s_setprio(1);                                                \
        _Pragma("unroll")                                                             \
        for (int mr = 0; mr < 4; ++mr) {                                              \
            acc[mr][0] = __builtin_amdgcn_mfma_i32_32x32x32_i8(af1[mr], BC[2], acc[mr][0], 0, 0, 0); \
            acc[mr][1] = __builtin_amdgcn_mfma_i32_32x32x32_i8(af1[mr], BC[3], acc[mr][1], 0, 0, 0); \
        }                                                                             \
        __builtin_amdgcn_s_setprio(0);                                                \
    }

__global__ __launch_bounds__(512, 2) void gemm_kernel(const uint8_t* __restrict__ xqS,
                                                      const uint8_t* __restrict__ wtS,
                                                      const float* __restrict__ xs,
                                                      const float* __restrict__ wsc,
                                                      const float* __restrict__ bias,
                                                      float* __restrict__ out) {
    __shared__ uint8_t ldsA[65536];   // 4 bufs * 16KB (A only)

    const int t    = threadIdx.x;
    const int lane = t & 63;
    const int wid  = t >> 6;
    const int wm   = wid >> 2, wn = wid & 3;   // wave tile: 128 rows x 64 cols

    int bid = blockIdx.x;
    bid = (bid & 7) * 256 + (bid >> 3);        // XCD swizzle (2048 % 8 == 0)
    const int mt = bid >> 6;
    const int nt = bid & 63;

    const uint8_t* aBase = xqS + (size_t)mt * (NKT * 16384);
    const uint8_t* bBase = wtS + (size_t)nt * (NKT * 16384);
    const int t16  = t * 16;
    const int wofs = wid * 1024;

    const int aRd0 = (lane >> 5) * 4096 + wm * 2048 + (lane & 31) * 16;
    const int bOff = (lane >> 5) * 4096 + wn * 1024 + (lane & 31) * 16;

    int32x16 acc[4][2] = {};
    int32x4 af0[4], af1[4], bfA[4], bfB[4];

    // prologue: stage A tiles 0,1,2; load B tile 0 into bfA
#pragma unroll
    for (int tt = 0; tt < 3; ++tt)
#pragma unroll
        for (int L = 0; L < 2; ++L)
            gload_lds16(aBase + tt * 16384 + L * 8192 + t16, ldsA + tt * 16384 + L * 8192 + wofs);
    {
        const uint8_t* bsrc = bBase + bOff;
        bfA[0] = *reinterpret_cast<const int32x4*>(bsrc);
        bfA[1] = *reinterpret_cast<const int32x4*>(bsrc + 512);
        bfA[2] = *reinterpret_cast<const int32x4*>(bsrc + 8192);
        bfA[3] = *reinterpret_cast<const int32x4*>(bsrc + 8704);
    }
    asm volatile("s_waitcnt vmcnt(8)" ::: "memory");   // A tile 0 landed
    __builtin_amdgcn_s_barrier();
    __builtin_amdgcn_sched_barrier(0);
#pragma unroll
    for (int mr = 0; mr < 4; ++mr)
        af0[mr] = *reinterpret_cast<const int32x4*>(ldsA + aRd0 + mr * 512);

    for (int kt2 = 0; kt2 < NKT; kt2 += 2) {
        GEMM_STEP(kt2,     bfA, bfB);
        GEMM_STEP(kt2 + 1, bfB, bfA);
    }

    // epilogue: C/D 32x32 layout: col = lane&31, row = (g&3)+8*(g>>2)+4*(lane>>5)
    const int row0 = mt * 256 + wm * 128;
    const int col0 = nt * 256 + wn * 64;
#pragma unroll
    for (int mr = 0; mr < 4; ++mr) {
        const int rbase = row0 + mr * 32 + 4 * (lane >> 5);
        float xsv[16];
#pragma unroll
        for (int g = 0; g < 16; ++g)
            xsv[g] = xs[rbase + (g & 3) + 8 * (g >> 2)];
#pragma unroll
        for (int nr = 0; nr < 2; ++nr) {
            const int n = col0 + nr * 32 + (lane & 31);
            const float ws_n = wsc[n];
            const float b_n  = bias[n];
#pragma unroll
            for (int g = 0; g < 16; ++g) {
                const int m = rbase + (g & 3) + 8 * (g >> 2);
                out[(size_t)m * OUT_F + n] = (float)acc[mr][nr][g] * xsv[g] * ws_n + b_n;
            }
        }
    }
}

// ---------------------------------------------------------------------------
extern "C" void kernel_launch(void* const* d_in, const int* in_sizes, int n_in,
                              void* d_out, int out_size, void* d_ws, size_t ws_size,
                              hipStream_t stream) {
    const float* x    = (const float*)d_in[0];
    const int*   wq   = (const int*)d_in[1];     // int8 pushed as int32 [4096][16384]
    const float* wsc  = (const float*)d_in[2];
    const float* bias = (const float*)d_in[3];
    float* out = (float*)d_out;

    uint8_t* ws  = (uint8_t*)d_ws;
    uint8_t* wtS = ws;                                               // 64 MiB
    uint8_t* xqS = ws + (size_t)IN_F * OUT_F;                        // 32 MiB
    float*   xs  = (float*)(ws + (size_t)IN_F * OUT_F + (size_t)NROWS * IN_F);

    transpose_kernel<<<dim3(OUT_F / 64, IN_F / 64), 256, 0, stream>>>(wq, wtS);
    quant_kernel<<<NROWS / 8, 256, 0, stream>>>(x, xqS, xs);
    gemm_kernel<<<(NROWS / 256) * (OUT_F / 256), 512, 0, stream>>>(xqS, wtS, xs, wsc, bias, out);
}

// Round 7
// 707.223 us; speedup vs baseline: 1.1060x; 1.1060x over previous
//
#include <hip/hip_runtime.h>
#include <cstdint>
#include <cstddef>

#define IN_F  4096
#define OUT_F 16384
#define NROWS 8192   // 2*4096 tokens
#define NKT   64     // K-tiles of 64 bytes

typedef __attribute__((ext_vector_type(4)))  int int32x4;
typedef __attribute__((ext_vector_type(16))) int int32x16;

// async global->LDS, 16B/lane (dest = wave-uniform base, HW adds lane*16)
__device__ __forceinline__ void gload_lds16(const void* g, void* s) {
    __builtin_amdgcn_global_load_lds((const __attribute__((address_space(1))) void*)g,
                                     (__attribute__((address_space(3))) void*)s,
                                     16, 0, 0);
}

// ---------------------------------------------------------------------------
// Layouts (fragment-major, shared by producers and GEMM staging):
//   xqS: [mtile 32][kt 64][c 4][row 256][16B]   c = ksub*2+kh, k = kt*64+c*16..+16
//   wtS: [ntile 64][kt 64][c 4][col 256][16B]
// ---------------------------------------------------------------------------

// Kernel 1: weight [K=4096][N=16384] int32 -> wtS (narrow + transpose + tile)
__global__ __launch_bounds__(256) void transpose_kernel(const int* __restrict__ w,
                                                        uint8_t* __restrict__ wtS) {
    __shared__ uint8_t tile[64][68];
    const int t  = threadIdx.x;
    const int nb = blockIdx.x * 64;
    const int kt = blockIdx.y;          // K-tile = 64 k-rows
    const int kb = kt * 64;

#pragma unroll
    for (int p = 0; p < 4; ++p) {
        const int r = p * 16 + (t >> 4);
        const int c4 = t & 15;
        int4 u = *reinterpret_cast<const int4*>(w + (size_t)(kb + r) * OUT_F + nb + c4 * 4);
        uint32_t packed = (uint32_t)(u.x & 255) | ((uint32_t)(u.y & 255) << 8)
                        | ((uint32_t)(u.z & 255) << 16) | ((uint32_t)(u.w & 255) << 24);
        *reinterpret_cast<uint32_t*>(&tile[r][c4 * 4]) = packed;
    }
    __syncthreads();

    const int col = t >> 2;             // 0..63
    const int c   = t & 3;              // ksub*2+kh
    uint4 o;
    uint32_t* op = reinterpret_cast<uint32_t*>(&o);
#pragma unroll
    for (int j = 0; j < 4; ++j) {
        const int kk = c * 16 + j * 4;
        op[j] = (uint32_t)tile[kk][col] | ((uint32_t)tile[kk + 1][col] << 8)
              | ((uint32_t)tile[kk + 2][col] << 16) | ((uint32_t)tile[kk + 3][col] << 24);
    }
    const int ntile = nb >> 8;
    const int colg  = (nb & 255) + col;
    *reinterpret_cast<uint4*>(wtS + (((size_t)ntile * NKT + kt) * 4 + c) * 4096 + colg * 16) = o;
}

// Kernel 2: per-row dynamic quant -> xqS (fragment-major) + xs
__global__ __launch_bounds__(256) void quant_kernel(const float* __restrict__ x,
                                                    uint8_t* __restrict__ xqS,
                                                    float* __restrict__ xs) {
    const int t = threadIdx.x;
    const int w = t >> 6, l = t & 63;
    const int half = l >> 5, lh = l & 31;
    const int m = blockIdx.x * 8 + w * 2 + half;
    const float* xr = x + (size_t)m * IN_F;

    float am = 0.0f;
#pragma unroll 8
    for (int jj = 0; jj < 32; ++jj) {
        float4 v = reinterpret_cast<const float4*>(xr)[jj * 32 + lh];
        am = fmaxf(am, fmaxf(fmaxf(fabsf(v.x), fabsf(v.y)),
                             fmaxf(fabsf(v.z), fabsf(v.w))));
    }
#pragma unroll
    for (int off = 16; off; off >>= 1) am = fmaxf(am, __shfl_xor(am, off));

    const float scale = fmaxf(am / 127.0f, 1e-12f);
    if (lh == 0) xs[m] = scale;

    const int mtile = m >> 8, mrow = m & 255;
    uint8_t* ob = xqS + (size_t)mtile * (NKT * 16384) + (size_t)mrow * 16;
#pragma unroll
    for (int j = 0; j < 8; ++j) {
        const int k0 = lh * 128 + j * 16;
        const float4* vp = reinterpret_cast<const float4*>(xr + k0);
        uint4 pk;
        uint32_t* pp = reinterpret_cast<uint32_t*>(&pk);
#pragma unroll
        for (int q = 0; q < 4; ++q) {
            float4 v = vp[q];
            float r0 = fminf(127.f, fmaxf(-128.f, rintf(v.x / scale)));
            float r1 = fminf(127.f, fmaxf(-128.f, rintf(v.y / scale)));
            float r2 = fminf(127.f, fmaxf(-128.f, rintf(v.z / scale)));
            float r3 = fminf(127.f, fmaxf(-128.f, rintf(v.w / scale)));
            pp[q] = ((uint32_t)((int)r0 & 255)) | ((uint32_t)((int)r1 & 255) << 8)
                  | ((uint32_t)((int)r2 & 255) << 16) | ((uint32_t)((int)r3 & 255) << 24);
        }
        const int ktk = k0 >> 6;
        const int c   = (k0 >> 4) & 3;
        *reinterpret_cast<uint4*>(ob + ((size_t)ktk * 4 + c) * 4096) = pk;
    }
}

// ---------------------------------------------------------------------------
// Kernel 3: int8 GEMM, 256x256 tile, 8 waves (2Mx4N), A+B quad-buffered LDS
// (128KB dynamic), depth-3 staging. Counted lgkmcnt(12) (DS in-order: the 12
// younger reads are f0(kt)+f1(kt); everything older — all tile kt-1 reads —
// is drained) so the LDS pipe is never flushed; staging issues post-barrier
// so the WAR needs only tile kt-1 drained. vmcnt(4) steady state.
// ---------------------------------------------------------------------------
__global__ __launch_bounds__(512, 2) void gemm_kernel(const uint8_t* __restrict__ xqS,
                                                      const uint8_t* __restrict__ wtS,
                                                      const float* __restrict__ xs,
                                                      const float* __restrict__ wsc,
                                                      const float* __restrict__ bias,
                                                      float* __restrict__ out) {
    extern __shared__ uint8_t lds[];
    uint8_t* ldsA = lds;            // 4 bufs * 16KB
    uint8_t* ldsB = lds + 65536;    // 4 bufs * 16KB

    const int t    = threadIdx.x;
    const int lane = t & 63;
    const int wid  = t >> 6;
    const int wm   = wid >> 2, wn = wid & 3;   // wave tile: 128 rows x 64 cols

    int bid = blockIdx.x;
    bid = (bid & 7) * 256 + (bid >> 3);        // XCD swizzle (2048 % 8 == 0)
    const int mt = bid >> 6;
    const int nt = bid & 63;

    const uint8_t* aBase = xqS + (size_t)mt * (NKT * 16384);
    const uint8_t* bBase = wtS + (size_t)nt * (NKT * 16384);
    const int t16  = t * 16;
    const int wofs = wid * 1024;

    const int aRd0 = (lane >> 5) * 4096 + wm * 2048 + (lane & 31) * 16;
    const int bRd0 = (lane >> 5) * 4096 + wn * 1024 + (lane & 31) * 16;

    int32x16 acc[4][2] = {};
    int32x4 af0[4], bf0[2], af1[4], bf1[2];

    // prologue: stage K-tiles 0,1,2 (tile-major vmcnt ledger)
#pragma unroll
    for (int tt = 0; tt < 3; ++tt)
#pragma unroll
        for (int L = 0; L < 2; ++L) {
            gload_lds16(aBase + tt * 16384 + L * 8192 + t16, ldsA + tt * 16384 + L * 8192 + wofs);
            gload_lds16(bBase + tt * 16384 + L * 8192 + t16, ldsB + tt * 16384 + L * 8192 + wofs);
        }
    asm volatile("s_waitcnt vmcnt(8)" ::: "memory");   // tile 0 landed
    __builtin_amdgcn_s_barrier();
    __builtin_amdgcn_sched_barrier(0);

    // fragments (tile 0, s=0) -> f0
#pragma unroll
    for (int mr = 0; mr < 4; ++mr)
        af0[mr] = *reinterpret_cast<const int32x4*>(ldsA + aRd0 + mr * 512);
#pragma unroll
    for (int nr = 0; nr < 2; ++nr)
        bf0[nr] = *reinterpret_cast<const int32x4*>(ldsB + bRd0 + nr * 512);

    for (int kt = 0; kt < NKT; ++kt) {
        const int q  = (kt & 3) * 16384;
        const int q1 = ((kt + 1) & 3) * 16384;
        const int q3 = ((kt + 3) & 3) * 16384;

        // 1. issue ds_reads (kt, s=1) -> f1 (overlap with MFMA f0 below)
#pragma unroll
        for (int mr = 0; mr < 4; ++mr)
            af1[mr] = *reinterpret_cast<const int32x4*>(ldsA + q + 8192 + aRd0 + mr * 512);
#pragma unroll
        for (int nr = 0; nr < 2; ++nr)
            bf1[nr] = *reinterpret_cast<const int32x4*>(ldsB + q + 8192 + bRd0 + nr * 512);

        // 2. MFMA cluster on f0 (LDS pipe serves f1 reads underneath)
        __builtin_amdgcn_s_setprio(1);
#pragma unroll
        for (int mr = 0; mr < 4; ++mr)
#pragma unroll
            for (int nr = 0; nr < 2; ++nr)
                acc[mr][nr] = __builtin_amdgcn_mfma_i32_32x32x32_i8(af0[mr], bf0[nr], acc[mr][nr], 0, 0, 0);
        __builtin_amdgcn_s_setprio(0);

        if (kt < NKT - 1) {
            // 3. counted DS drain: 12 younger reads (f0(kt)+f1(kt)) may stay in
            //    flight; all reads of buf[(kt+3)&3] (= tile kt-1) are done.
            asm volatile("s_waitcnt lgkmcnt(12)" ::: "memory");
            // 4. counted vmcnt: tile kt+1 (staged 2 iters ago) landed.
            if (kt < NKT - 2) asm volatile("s_waitcnt vmcnt(4)" ::: "memory");
            else              asm volatile("s_waitcnt vmcnt(0)" ::: "memory");
            __builtin_amdgcn_s_barrier();
            __builtin_amdgcn_sched_barrier(0);   // pin stage + reads below barrier

            // 5. stage tile kt+3 (WAR-safe per step 3 across the barrier)
            if (kt < NKT - 3) {
                const size_t src3 = (size_t)(kt + 3) * 16384;
#pragma unroll
                for (int L = 0; L < 2; ++L) {
                    gload_lds16(aBase + src3 + L * 8192 + t16, ldsA + q3 + L * 8192 + wofs);
                    gload_lds16(bBase + src3 + L * 8192 + t16, ldsB + q3 + L * 8192 + wofs);
                }
            }

            // 6. issue ds_reads (kt+1, s=0) -> f0 (overlap with MFMA f1 below)
#pragma unroll
            for (int mr = 0; mr < 4; ++mr)
                af0[mr] = *reinterpret_cast<const int32x4*>(ldsA + q1 + aRd0 + mr * 512);
#pragma unroll
            for (int nr = 0; nr < 2; ++nr)
                bf0[nr] = *reinterpret_cast<const int32x4*>(ldsB + q1 + bRd0 + nr * 512);
        }

        // 7. MFMA cluster on f1
        __builtin_amdgcn_s_setprio(1);
#pragma unroll
        for (int mr = 0; mr < 4; ++mr)
#pragma unroll
            for (int nr = 0; nr < 2; ++nr)
                acc[mr][nr] = __builtin_amdgcn_mfma_i32_32x32x32_i8(af1[mr], bf1[nr], acc[mr][nr], 0, 0, 0);
        __builtin_amdgcn_s_setprio(0);
    }

    // epilogue: C/D 32x32 layout: col = lane&31, row = (g&3)+8*(g>>2)+4*(lane>>5)
    const int row0 = mt * 256 + wm * 128;
    const int col0 = nt * 256 + wn * 64;
#pragma unroll
    for (int mr = 0; mr < 4; ++mr) {
        const int rbase = row0 + mr * 32 + 4 * (lane >> 5);
        float xsv[16];
#pragma unroll
        for (int g = 0; g < 16; ++g)
            xsv[g] = xs[rbase + (g & 3) + 8 * (g >> 2)];
#pragma unroll
        for (int nr = 0; nr < 2; ++nr) {
            const int n = col0 + nr * 32 + (lane & 31);
            const float ws_n = wsc[n];
            const float b_n  = bias[n];
#pragma unroll
            for (int g = 0; g < 16; ++g) {
                const int m = rbase + (g & 3) + 8 * (g >> 2);
                out[(size_t)m * OUT_F + n] = (float)acc[mr][nr][g] * xsv[g] * ws_n + b_n;
            }
        }
    }
}

// ---------------------------------------------------------------------------
extern "C" void kernel_launch(void* const* d_in, const int* in_sizes, int n_in,
                              void* d_out, int out_size, void* d_ws, size_t ws_size,
                              hipStream_t stream) {
    const float* x    = (const float*)d_in[0];
    const int*   wq   = (const int*)d_in[1];     // int8 pushed as int32 [4096][16384]
    const float* wsc  = (const float*)d_in[2];
    const float* bias = (const float*)d_in[3];
    float* out = (float*)d_out;

    uint8_t* ws  = (uint8_t*)d_ws;
    uint8_t* wtS = ws;                                               // 64 MiB
    uint8_t* xqS = ws + (size_t)IN_F * OUT_F;                        // 32 MiB
    float*   xs  = (float*)(ws + (size_t)IN_F * OUT_F + (size_t)NROWS * IN_F);

    (void)hipFuncSetAttribute((const void*)gemm_kernel,
                              hipFuncAttributeMaxDynamicSharedMemorySize, 131072);

    transpose_kernel<<<dim3(OUT_F / 64, IN_F / 64), 256, 0, stream>>>(wq, wtS);
    quant_kernel<<<NROWS / 8, 256, 0, stream>>>(x, xqS, xs);
    gemm_kernel<<<(NROWS / 256) * (OUT_F / 256), 512, 131072, stream>>>(xqS, wtS, xs, wsc, bias, out);
}

// Round 8
// 674.908 us; speedup vs baseline: 1.1590x; 1.0479x over previous
//
#include <hip/hip_runtime.h>
#include <cstdint>
#include <cstddef>

#define IN_F  4096
#define OUT_F 16384
#define NROWS 8192   // 2*4096 tokens
#define NKT   64     // K-tiles of 64 bytes

typedef __attribute__((ext_vector_type(4)))  int int32x4;
typedef __attribute__((ext_vector_type(16))) int int32x16;

// async global->LDS, 16B/lane (dest = wave-uniform base, HW adds lane*16)
__device__ __forceinline__ void gload_lds16(const void* g, void* s) {
    __builtin_amdgcn_global_load_lds((const __attribute__((address_space(1))) void*)g,
                                     (__attribute__((address_space(3))) void*)s,
                                     16, 0, 0);
}

// ---------------------------------------------------------------------------
// Layouts (fragment-major, shared by producers and GEMM staging):
//   xqS: [mtile 32][kt 64][c 4][row 256][16B]   c = ksub*2+kh, k = kt*64+c*16..+16
//   wtS: [ntile 64][kt 64][c 4][col 256][16B]
// ---------------------------------------------------------------------------

// Kernel 1: weight [K=4096][N=16384] int32 -> wtS (narrow + transpose + tile)
__global__ __launch_bounds__(256) void transpose_kernel(const int* __restrict__ w,
                                                        uint8_t* __restrict__ wtS) {
    __shared__ uint8_t tile[64][68];
    const int t  = threadIdx.x;
    const int nb = blockIdx.x * 64;
    const int kt = blockIdx.y;          // K-tile = 64 k-rows
    const int kb = kt * 64;

#pragma unroll
    for (int p = 0; p < 4; ++p) {
        const int r = p * 16 + (t >> 4);
        const int c4 = t & 15;
        int4 u = *reinterpret_cast<const int4*>(w + (size_t)(kb + r) * OUT_F + nb + c4 * 4);
        uint32_t packed = (uint32_t)(u.x & 255) | ((uint32_t)(u.y & 255) << 8)
                        | ((uint32_t)(u.z & 255) << 16) | ((uint32_t)(u.w & 255) << 24);
        *reinterpret_cast<uint32_t*>(&tile[r][c4 * 4]) = packed;
    }
    __syncthreads();

    const int col = t >> 2;             // 0..63
    const int c   = t & 3;              // ksub*2+kh
    uint4 o;
    uint32_t* op = reinterpret_cast<uint32_t*>(&o);
#pragma unroll
    for (int j = 0; j < 4; ++j) {
        const int kk = c * 16 + j * 4;
        op[j] = (uint32_t)tile[kk][col] | ((uint32_t)tile[kk + 1][col] << 8)
              | ((uint32_t)tile[kk + 2][col] << 16) | ((uint32_t)tile[kk + 3][col] << 24);
    }
    const int ntile = nb >> 8;
    const int colg  = (nb & 255) + col;
    *reinterpret_cast<uint4*>(wtS + (((size_t)ntile * NKT + kt) * 4 + c) * 4096 + colg * 16) = o;
}

// Kernel 2: per-row dynamic quant -> xqS (fragment-major) + xs
__global__ __launch_bounds__(256) void quant_kernel(const float* __restrict__ x,
                                                    uint8_t* __restrict__ xqS,
                                                    float* __restrict__ xs) {
    const int t = threadIdx.x;
    const int w = t >> 6, l = t & 63;
    const int half = l >> 5, lh = l & 31;
    const int m = blockIdx.x * 8 + w * 2 + half;
    const float* xr = x + (size_t)m * IN_F;

    float am = 0.0f;
#pragma unroll 8
    for (int jj = 0; jj < 32; ++jj) {
        float4 v = reinterpret_cast<const float4*>(xr)[jj * 32 + lh];
        am = fmaxf(am, fmaxf(fmaxf(fabsf(v.x), fabsf(v.y)),
                             fmaxf(fabsf(v.z), fabsf(v.w))));
    }
#pragma unroll
    for (int off = 16; off; off >>= 1) am = fmaxf(am, __shfl_xor(am, off));

    const float scale = fmaxf(am / 127.0f, 1e-12f);
    if (lh == 0) xs[m] = scale;

    const int mtile = m >> 8, mrow = m & 255;
    uint8_t* ob = xqS + (size_t)mtile * (NKT * 16384) + (size_t)mrow * 16;
#pragma unroll
    for (int j = 0; j < 8; ++j) {
        const int k0 = lh * 128 + j * 16;
        const float4* vp = reinterpret_cast<const float4*>(xr + k0);
        uint4 pk;
        uint32_t* pp = reinterpret_cast<uint32_t*>(&pk);
#pragma unroll
        for (int q = 0; q < 4; ++q) {
            float4 v = vp[q];
            float r0 = fminf(127.f, fmaxf(-128.f, rintf(v.x / scale)));
            float r1 = fminf(127.f, fmaxf(-128.f, rintf(v.y / scale)));
            float r2 = fminf(127.f, fmaxf(-128.f, rintf(v.z / scale)));
            float r3 = fminf(127.f, fmaxf(-128.f, rintf(v.w / scale)));
            pp[q] = ((uint32_t)((int)r0 & 255)) | ((uint32_t)((int)r1 & 255) << 8)
                  | ((uint32_t)((int)r2 & 255) << 16) | ((uint32_t)((int)r3 & 255) << 24);
        }
        const int ktk = k0 >> 6;
        const int c   = (k0 >> 4) & 3;
        *reinterpret_cast<uint4*>(ob + ((size_t)ktk * 4 + c) * 4096) = pk;
    }
}

// ---------------------------------------------------------------------------
// Kernel 3: int8 GEMM, 256x256 tile, 8 waves (2Mx4N), A+B quad-buffered LDS
// (128KB dynamic), depth-3 staging, reg-double-buffered fragments (round-5
// schedule — best measured). NEW: nt-outer intra-XCD tile order — the 4
// mt-neighbors sharing a B panel run concurrently on one XCD, so each 1MB
// B panel is fetched into L2 once instead of 4x.
// ---------------------------------------------------------------------------
__global__ __launch_bounds__(512, 2) void gemm_kernel(const uint8_t* __restrict__ xqS,
                                                      const uint8_t* __restrict__ wtS,
                                                      const float* __restrict__ xs,
                                                      const float* __restrict__ wsc,
                                                      const float* __restrict__ bias,
                                                      float* __restrict__ out) {
    extern __shared__ uint8_t lds[];
    uint8_t* ldsA = lds;            // 4 bufs * 16KB
    uint8_t* ldsB = lds + 65536;    // 4 bufs * 16KB

    const int t    = threadIdx.x;
    const int lane = t & 63;
    const int wid  = t >> 6;
    const int wm   = wid >> 2, wn = wid & 3;   // wave tile: 128 rows x 64 cols

    // XCD-aware mapping (2048 blocks, 8 XCDs round-robin on orig bid):
    // XCD x owns mt rows 4x..4x+3 (A panels L2-resident); locals advance
    // nt-outer so 4 concurrent neighbors share each 1MB B panel in L2.
    const int xcd = blockIdx.x & 7;
    const int i   = blockIdx.x >> 3;           // 0..255 local on this XCD
    const int mt  = xcd * 4 + (i & 3);         // 0..31
    const int nt  = i >> 2;                    // 0..63

    const uint8_t* aBase = xqS + (size_t)mt * (NKT * 16384);
    const uint8_t* bBase = wtS + (size_t)nt * (NKT * 16384);
    const int t16  = t * 16;
    const int wofs = wid * 1024;

    const int aRd0 = (lane >> 5) * 4096 + wm * 2048 + (lane & 31) * 16;
    const int bRd0 = (lane >> 5) * 4096 + wn * 1024 + (lane & 31) * 16;

    int32x16 acc[4][2] = {};
    int32x4 af0[4], bf0[2], af1[4], bf1[2];

    // prologue: stage K-tiles 0,1,2 (tile-major vmcnt ledger)
#pragma unroll
    for (int tt = 0; tt < 3; ++tt)
#pragma unroll
        for (int L = 0; L < 2; ++L) {
            gload_lds16(aBase + tt * 16384 + L * 8192 + t16, ldsA + tt * 16384 + L * 8192 + wofs);
            gload_lds16(bBase + tt * 16384 + L * 8192 + t16, ldsB + tt * 16384 + L * 8192 + wofs);
        }
    asm volatile("s_waitcnt vmcnt(8)" ::: "memory");   // tile 0 landed
    __builtin_amdgcn_s_barrier();
    __builtin_amdgcn_sched_barrier(0);

    // fragments (tile 0, s=0) -> f0
#pragma unroll
    for (int mr = 0; mr < 4; ++mr)
        af0[mr] = *reinterpret_cast<const int32x4*>(ldsA + aRd0 + mr * 512);
#pragma unroll
    for (int nr = 0; nr < 2; ++nr)
        bf0[nr] = *reinterpret_cast<const int32x4*>(ldsB + bRd0 + nr * 512);

    for (int kt = 0; kt < NKT; ++kt) {
        const int q  = (kt & 3) * 16384;
        const int q1 = ((kt + 1) & 3) * 16384;
        const int q3 = ((kt + 3) & 3) * 16384;

        // 1. issue ds_reads (kt, s=1) -> f1 (overlap with MFMA f0 below)
#pragma unroll
        for (int mr = 0; mr < 4; ++mr)
            af1[mr] = *reinterpret_cast<const int32x4*>(ldsA + q + 8192 + aRd0 + mr * 512);
#pragma unroll
        for (int nr = 0; nr < 2; ++nr)
            bf1[nr] = *reinterpret_cast<const int32x4*>(ldsB + q + 8192 + bRd0 + nr * 512);

        // 2. stage tile kt+3 (buffer freed: all reads of tile kt-1 drained
        //    before last iteration's barrier via lgkmcnt(0))
        if (kt < NKT - 3) {
            const size_t src3 = (size_t)(kt + 3) * 16384;
#pragma unroll
            for (int L = 0; L < 2; ++L) {
                gload_lds16(aBase + src3 + L * 8192 + t16, ldsA + q3 + L * 8192 + wofs);
                gload_lds16(bBase + src3 + L * 8192 + t16, ldsB + q3 + L * 8192 + wofs);
            }
        }

        // 3. MFMA cluster on f0 (LDS pipe works on f1's reads meanwhile)
        __builtin_amdgcn_s_setprio(1);
#pragma unroll
        for (int mr = 0; mr < 4; ++mr)
#pragma unroll
            for (int nr = 0; nr < 2; ++nr)
                acc[mr][nr] = __builtin_amdgcn_mfma_i32_32x32x32_i8(af0[mr], bf0[nr], acc[mr][nr], 0, 0, 0);
        __builtin_amdgcn_s_setprio(0);

        if (kt < NKT - 1) {
            // 4. drain my ds_reads (WAR: next iter overwrites buf[kt-1]-class slot)
            asm volatile("s_waitcnt lgkmcnt(0)" ::: "memory");
            // 5. counted vmcnt: tile kt+1 (issued 2 iters ago) landed; never 0 mid-loop
            if (kt < NKT - 3)       asm volatile("s_waitcnt vmcnt(8)" ::: "memory");
            else if (kt == NKT - 3) asm volatile("s_waitcnt vmcnt(4)" ::: "memory");
            else                    asm volatile("s_waitcnt vmcnt(0)" ::: "memory");
            __builtin_amdgcn_s_barrier();
            __builtin_amdgcn_sched_barrier(0);   // pin reads below barrier

            // 6. issue ds_reads (kt+1, s=0) -> f0 (overlap with MFMA f1 below)
#pragma unroll
            for (int mr = 0; mr < 4; ++mr)
                af0[mr] = *reinterpret_cast<const int32x4*>(ldsA + q1 + aRd0 + mr * 512);
#pragma unroll
            for (int nr = 0; nr < 2; ++nr)
                bf0[nr] = *reinterpret_cast<const int32x4*>(ldsB + q1 + bRd0 + nr * 512);
        }

        // 7. MFMA cluster on f1
        __builtin_amdgcn_s_setprio(1);
#pragma unroll
        for (int mr = 0; mr < 4; ++mr)
#pragma unroll
            for (int nr = 0; nr < 2; ++nr)
                acc[mr][nr] = __builtin_amdgcn_mfma_i32_32x32x32_i8(af1[mr], bf1[nr], acc[mr][nr], 0, 0, 0);
        __builtin_amdgcn_s_setprio(0);
    }

    // epilogue: C/D 32x32 layout: col = lane&31, row = (g&3)+8*(g>>2)+4*(lane>>5)
    const int row0 = mt * 256 + wm * 128;
    const int col0 = nt * 256 + wn * 64;
#pragma unroll
    for (int mr = 0; mr < 4; ++mr) {
        const int rbase = row0 + mr * 32 + 4 * (lane >> 5);
        float xsv[16];
#pragma unroll
        for (int g = 0; g < 16; ++g)
            xsv[g] = xs[rbase + (g & 3) + 8 * (g >> 2)];
#pragma unroll
        for (int nr = 0; nr < 2; ++nr) {
            const int n = col0 + nr * 32 + (lane & 31);
            const float ws_n = wsc[n];
            const float b_n  = bias[n];
#pragma unroll
            for (int g = 0; g < 16; ++g) {
                const int m = rbase + (g & 3) + 8 * (g >> 2);
                out[(size_t)m * OUT_F + n] = (float)acc[mr][nr][g] * xsv[g] * ws_n + b_n;
            }
        }
    }
}

// ---------------------------------------------------------------------------
extern "C" void kernel_launch(void* const* d_in, const int* in_sizes, int n_in,
                              void* d_out, int out_size, void* d_ws, size_t ws_size,
                              hipStream_t stream) {
    const float* x    = (const float*)d_in[0];
    const int*   wq   = (const int*)d_in[1];     // int8 pushed as int32 [4096][16384]
    const float* wsc  = (const float*)d_in[2];
    const float* bias = (const float*)d_in[3];
    float* out = (float*)d_out;

    uint8_t* ws  = (uint8_t*)d_ws;
    uint8_t* wtS = ws;                                               // 64 MiB
    uint8_t* xqS = ws + (size_t)IN_F * OUT_F;                        // 32 MiB
    float*   xs  = (float*)(ws + (size_t)IN_F * OUT_F + (size_t)NROWS * IN_F);

    (void)hipFuncSetAttribute((const void*)gemm_kernel,
                              hipFuncAttributeMaxDynamicSharedMemorySize, 131072);

    transpose_kernel<<<dim3(OUT_F / 64, IN_F / 64), 256, 0, stream>>>(wq, wtS);
    quant_kernel<<<NROWS / 8, 256, 0, stream>>>(x, xqS, xs);
    gemm_kernel<<<(NROWS / 256) * (OUT_F / 256), 512, 131072, stream>>>(xqS, wtS, xs, wsc, bias, out);
}